// Round 1
// baseline (260.662 us; speedup 1.0000x reference)
//
#include <hip/hip_runtime.h>
#include <hip/hip_bf16.h>

// ---------- types ----------
typedef short  s16x8  __attribute__((ext_vector_type(8)));   // 8 bf16 (4 VGPR)
typedef float  f32x4  __attribute__((ext_vector_type(4)));
typedef float  f32x16 __attribute__((ext_vector_type(16)));
typedef unsigned int u32x4 __attribute__((ext_vector_type(4)));
using u32 = unsigned int;
using u16 = unsigned short;
using as3u = __attribute__((address_space(3))) unsigned int;
using as1u = __attribute__((address_space(1))) unsigned int;

#define FINF __builtin_inff()

// problem constants
constexpr int B_  = 8;
constexpr int N_  = 2048;
constexpr int C_  = 384;
constexpr int H_  = 6;
constexpr int D_  = 64;
constexpr int BN_ = B_ * N_;        // 16384 tokens
constexpr int O3_ = 3 * C_;         // 1152
constexpr int NW1 = O3_ * C_;       // 442368 qkv weights
constexpr int NW2 = C_ * C_;        // 147456 proj weights

__device__ __forceinline__ u16 f2bf(float f) {
    union { float f; u32 u; } v; v.f = f;
    u32 r = v.u + 0x7FFFu + ((v.u >> 16) & 1u);   // RNE
    return (u16)(r >> 16);
}
__device__ __forceinline__ u32 pck(float a, float b) {
    return (u32)f2bf(a) | ((u32)f2bf(b) << 16);
}

// ---------- weight absmean (double partials for stability) ----------
__global__ void k_wstats(const float* __restrict__ w1, const float* __restrict__ w2,
                         double* __restrict__ partial) {
    double s1 = 0.0, s2 = 0.0;
    int t = blockIdx.x * 256 + threadIdx.x;
    const int stride = 256 * 256;
    for (int i = t; i < NW1; i += stride) s1 += (double)fabsf(w1[i]);
    for (int i = t; i < NW2; i += stride) s2 += (double)fabsf(w2[i]);
#pragma unroll
    for (int m = 1; m < 64; m <<= 1) { s1 += __shfl_xor(s1, m, 64); s2 += __shfl_xor(s2, m, 64); }
    __shared__ double r1[4], r2[4];
    int wid = threadIdx.x >> 6;
    if ((threadIdx.x & 63) == 0) { r1[wid] = s1; r2[wid] = s2; }
    __syncthreads();
    if (threadIdx.x == 0) {
        partial[2 * blockIdx.x]     = r1[0] + r1[1] + r1[2] + r1[3];
        partial[2 * blockIdx.x + 1] = r2[0] + r2[1] + r2[2] + r2[3];
    }
}

__global__ void k_wfinal(const double* __restrict__ partial, float* __restrict__ scales) {
    int t = threadIdx.x;  // 256 threads, 256 partial pairs
    double s1 = partial[2 * t], s2 = partial[2 * t + 1];
#pragma unroll
    for (int m = 1; m < 64; m <<= 1) { s1 += __shfl_xor(s1, m, 64); s2 += __shfl_xor(s2, m, 64); }
    __shared__ double r1[4], r2[4];
    if ((t & 63) == 0) { r1[t >> 6] = s1; r2[t >> 6] = s2; }
    __syncthreads();
    if (t == 0) {
        float m1 = (float)((r1[0] + r1[1] + r1[2] + r1[3]) / (double)NW1);
        float m2 = (float)((r2[0] + r2[1] + r2[2] + r2[3]) / (double)NW2);
        float sc1 = 1.f / fmaxf(m1, 1e-5f);
        float sc2 = 1.f / fmaxf(m2, 1e-5f);
        scales[0] = sc1; scales[1] = 1.f / sc1;
        scales[2] = sc2; scales[3] = 1.f / sc2;
    }
}

// ---------- ternary weight quant -> bf16 {-1,0,1} ----------
__global__ void k_wquant(const float* __restrict__ w1, const float* __restrict__ w2,
                         const float* __restrict__ scales,
                         u16* __restrict__ o1, u16* __restrict__ o2) {
    float sc1 = scales[0], sc2 = scales[2];
    int t = blockIdx.x * blockDim.x + threadIdx.x;
    int stride = gridDim.x * blockDim.x;
    for (int i = t; i < NW1; i += stride)
        o1[i] = f2bf(fminf(fmaxf(rintf(w1[i] * sc1), -1.f), 1.f));
    for (int i = t; i < NW2; i += stride)
        o2[i] = f2bf(fminf(fmaxf(rintf(w2[i] * sc2), -1.f), 1.f));
}

// ---------- per-token act quant: fp32 row(384) -> int-valued bf16 + 1/scale ----------
__global__ __launch_bounds__(128) void k_aquant(const float* __restrict__ in,
                                                u16* __restrict__ outq,
                                                float* __restrict__ rs) {
    int row = blockIdx.x;
    const float* xr = in + (size_t)row * C_;
    int t = threadIdx.x;
    float4 v = make_float4(0.f, 0.f, 0.f, 0.f);
    if (t < 96) v = ((const float4*)xr)[t];
    float mx = fmaxf(fmaxf(fabsf(v.x), fabsf(v.y)), fmaxf(fabsf(v.z), fabsf(v.w)));
#pragma unroll
    for (int m = 1; m < 64; m <<= 1) mx = fmaxf(mx, __shfl_xor(mx, m, 64));
    __shared__ float red[2];
    if ((t & 63) == 0) red[t >> 6] = mx;
    __syncthreads();
    mx = fmaxf(red[0], red[1]);
    float scale = 128.f / fmaxf(mx, 1e-5f);
    if (t == 0) rs[row] = 1.f / scale;
    if (t < 96) {
        ushort4 o;
        o.x = f2bf(fminf(fmaxf(rintf(v.x * scale), -128.f), 127.f));
        o.y = f2bf(fminf(fmaxf(rintf(v.y * scale), -128.f), 127.f));
        o.z = f2bf(fminf(fmaxf(rintf(v.z * scale), -128.f), 127.f));
        o.w = f2bf(fminf(fmaxf(rintf(v.w * scale), -128.f), 127.f));
        ((ushort4*)(outq + (size_t)row * C_))[t] = o;
    }
}

// ---------- GEMM: C[m,o] = sum_c A[m,c]*W[o,c]; dequant epilogue ----------
// MODE 0: N=1152, scatter to q(scaled 1/8)/k [bh][n][d] and v^T [bh][d][n] (bf16)
// MODE 1: N=384, write fp32 out
template <int MODE>
__global__ __launch_bounds__(256) void k_gemm(const u16* __restrict__ A, const u16* __restrict__ W,
                                              const float* __restrict__ rs, const float* __restrict__ scales,
                                              const float* __restrict__ bias,
                                              u16* __restrict__ qg, u16* __restrict__ kg, u16* __restrict__ vtg,
                                              float* __restrict__ fout) {
    constexpr int K = C_;
    __shared__ u16 As[128 * 64];
    __shared__ u16 Bs[128 * 64];
    int m0 = blockIdx.x * 128, n0 = blockIdx.y * 128;
    int tid = threadIdx.x, lane = tid & 63, wid = tid >> 6;
    int wm = wid >> 1, wn = wid & 1;

    f32x4 acc[4][4];
#pragma unroll
    for (int a = 0; a < 4; ++a)
#pragma unroll
        for (int b = 0; b < 4; ++b)
#pragma unroll
            for (int r = 0; r < 4; ++r) acc[a][b][r] = 0.f;

    for (int k0 = 0; k0 < K; k0 += 64) {
#pragma unroll
        for (int t = 0; t < 4; ++t) {
            int chunk = t * 256 + wid * 64 + lane;       // 16B chunks, per-lane
            int row = chunk >> 3, c8 = chunk & 7;
            const u16* srcA = A + (size_t)(m0 + row) * K + k0 + c8 * 8;
            const u16* srcB = W + (size_t)(n0 + row) * K + k0 + c8 * 8;
            __builtin_amdgcn_global_load_lds((const as1u*)srcA, (as3u*)(As + (size_t)(t * 256 + wid * 64) * 8), 16, 0, 0);
            __builtin_amdgcn_global_load_lds((const as1u*)srcB, (as3u*)(Bs + (size_t)(t * 256 + wid * 64) * 8), 16, 0, 0);
        }
        __syncthreads();
#pragma unroll
        for (int kk = 0; kk < 2; ++kk) {
            s16x8 ar[4], br[4];
#pragma unroll
            for (int f = 0; f < 4; ++f) {
                ar[f] = *(const s16x8*)(As + (wm * 64 + f * 16 + (lane & 15)) * 64 + kk * 32 + (lane >> 4) * 8);
                br[f] = *(const s16x8*)(Bs + (wn * 64 + f * 16 + (lane & 15)) * 64 + kk * 32 + (lane >> 4) * 8);
            }
#pragma unroll
            for (int fr = 0; fr < 4; ++fr)
#pragma unroll
                for (int fc = 0; fc < 4; ++fc)
                    acc[fr][fc] = __builtin_amdgcn_mfma_f32_16x16x32_bf16(ar[fr], br[fc], acc[fr][fc], 0, 0, 0);
        }
        __syncthreads();
    }

    float rsw = scales[MODE == 0 ? 1 : 3];
    int colg = lane & 15, rowb = (lane >> 4) * 4;
#pragma unroll
    for (int fr = 0; fr < 4; ++fr) {
#pragma unroll
        for (int r = 0; r < 4; ++r) {
            int m = m0 + wm * 64 + fr * 16 + rowb + r;
            float rsm = rs[m] * rsw;
#pragma unroll
            for (int fc = 0; fc < 4; ++fc) {
                int o = n0 + wn * 64 + fc * 16 + colg;
                float val = acc[fr][fc][r] * rsm + bias[o];
                if (MODE == 0) {
                    int b = m >> 11, n = m & 2047;
                    if (o < C_) {
                        int hh = o >> 6, d = o & 63;
                        qg[(size_t)(b * H_ + hh) * (N_ * D_) + n * 64 + d] = f2bf(val * 0.125f);
                    } else if (o < 2 * C_) {
                        int oo = o - C_; int hh = oo >> 6, d = oo & 63;
                        kg[(size_t)(b * H_ + hh) * (N_ * D_) + n * 64 + d] = f2bf(val);
                    } else {
                        int oo = o - 2 * C_; int hh = oo >> 6, d = oo & 63;
                        vtg[(size_t)(b * H_ + hh) * (N_ * D_) + (size_t)d * N_ + n] = f2bf(val);
                    }
                } else {
                    fout[(size_t)m * C_ + o] = val;
                }
            }
        }
    }
}

// ---------- flash attention: S^T = K.Q^T (swapped), softmax in-lane, O^T = V^T.P^T ----------
// grid: 48 bh * 16 qtiles(128 rows), block = 128 thr (2 waves, 64 q-rows each)
__global__ __launch_bounds__(128) void k_flash(const u16* __restrict__ qg, const u16* __restrict__ kg,
                                               const u16* __restrict__ vtg, float* __restrict__ attn) {
    int i = blockIdx.x;
    int bh = (i & 7) * 6 + ((i >> 3) % 6);   // same-bh blocks share XCD (i%8 fixed)
    int qt = (i >> 3) / 6;                   // 0..15
    int lane = threadIdx.x & 63;
    int wid = threadIdx.x >> 6;              // 0..1
    int h = lane >> 5;                       // lane half
    int ql = lane & 31;
    const u16* Qb = qg + (size_t)bh * (N_ * D_);
    const u16* Kb = kg + (size_t)bh * (N_ * D_);
    const u16* Vb = vtg + (size_t)bh * (N_ * D_);
    int q0 = qt * 128 + wid * 64;

    // Q^T B-frags, resident: qf[qb][cs], element j: Q[q0+qb*32+ql][cs*16+h*8+j]
    s16x8 qf[2][4];
#pragma unroll
    for (int qb = 0; qb < 2; ++qb)
#pragma unroll
        for (int cs = 0; cs < 4; ++cs)
            qf[qb][cs] = *(const s16x8*)(Qb + (size_t)(q0 + qb * 32 + ql) * 64 + cs * 16 + h * 8);

    f32x16 od[2][2];   // [db][qb], O^T acc: col=q(lane&31), row=d
#pragma unroll
    for (int a = 0; a < 2; ++a)
#pragma unroll
        for (int b = 0; b < 2; ++b)
#pragma unroll
            for (int r = 0; r < 16; ++r) od[a][b][r] = 0.f;

    float mrun[2] = { -FINF, -FINF };
    float lrun[2] = { 0.f, 0.f };

    for (int kv0 = 0; kv0 < N_; kv0 += 64) {
        s16x8 kf[2][4], vf[2][4];
#pragma unroll
        for (int kb = 0; kb < 2; ++kb)
#pragma unroll
            for (int cs = 0; cs < 4; ++cs)
                kf[kb][cs] = *(const s16x8*)(Kb + (size_t)(kv0 + kb * 32 + ql) * 64 + cs * 16 + h * 8);
#pragma unroll
        for (int db = 0; db < 2; ++db)
#pragma unroll
            for (int ks = 0; ks < 4; ++ks)
                vf[db][ks] = *(const s16x8*)(Vb + (size_t)(db * 32 + ql) * N_ + kv0 + ks * 16 + h * 8);

#pragma unroll
        for (int qb = 0; qb < 2; ++qb) {
            f32x16 s[2];
#pragma unroll
            for (int kb = 0; kb < 2; ++kb) {
#pragma unroll
                for (int r = 0; r < 16; ++r) s[kb][r] = 0.f;
#pragma unroll
                for (int cs = 0; cs < 4; ++cs)
                    s[kb] = __builtin_amdgcn_mfma_f32_32x32x16_bf16(kf[kb][cs], qf[qb][cs], s[kb], 0, 0, 0);
            }
            // online softmax; lane's k-rows: k = kb*32 + (r&3)+8*(r>>2)+4*h
            float mx = -FINF;
#pragma unroll
            for (int kb = 0; kb < 2; ++kb)
#pragma unroll
                for (int r = 0; r < 16; ++r) mx = fmaxf(mx, s[kb][r]);
            mx = fmaxf(mx, __shfl_xor(mx, 32, 64));
            float mnew = fmaxf(mrun[qb], mx);
            float fsc = __expf(mrun[qb] - mnew);
            float psum = 0.f;
#pragma unroll
            for (int kb = 0; kb < 2; ++kb)
#pragma unroll
                for (int r = 0; r < 16; ++r) {
                    float p = __expf(s[kb][r] - mnew);
                    s[kb][r] = p; psum += p;
                }
            lrun[qb] = lrun[qb] * fsc + psum;
            mrun[qb] = mnew;
#pragma unroll
            for (int db = 0; db < 2; ++db)
#pragma unroll
                for (int r = 0; r < 16; ++r) od[db][qb][r] *= fsc;
            // P^T B-frags: per ks, k-run h*8+j; exchange halves via shfl_xor(32)
#pragma unroll
            for (int ks = 0; ks < 4; ++ks) {
                const int kb = ks >> 1, rb = (ks & 1) * 8;
                u32 lo01 = pck(s[kb][rb + 0], s[kb][rb + 1]);
                u32 lo23 = pck(s[kb][rb + 2], s[kb][rb + 3]);
                u32 hi01 = pck(s[kb][rb + 4], s[kb][rb + 5]);
                u32 hi23 = pck(s[kb][rb + 6], s[kb][rb + 7]);
                u32 plo01 = (u32)__shfl_xor((int)lo01, 32, 64);
                u32 plo23 = (u32)__shfl_xor((int)lo23, 32, 64);
                u32 phi01 = (u32)__shfl_xor((int)hi01, 32, 64);
                u32 phi23 = (u32)__shfl_xor((int)hi23, 32, 64);
                u32x4 pw;
                pw[0] = h ? phi01 : lo01;
                pw[1] = h ? phi23 : lo23;
                pw[2] = h ? hi01 : plo01;
                pw[3] = h ? hi23 : plo23;
                s16x8 pf = __builtin_bit_cast(s16x8, pw);
                od[0][qb] = __builtin_amdgcn_mfma_f32_32x32x16_bf16(vf[0][ks], pf, od[0][qb], 0, 0, 0);
                od[1][qb] = __builtin_amdgcn_mfma_f32_32x32x16_bf16(vf[1][ks], pf, od[1][qb], 0, 0, 0);
            }
        }
    }

    int b = bh / H_, head = bh % H_;
#pragma unroll
    for (int qb = 0; qb < 2; ++qb) {
        float ltot = lrun[qb] + __shfl_xor(lrun[qb], 32, 64);
        float inv = 1.f / ltot;
        int q = q0 + qb * 32 + ql;
        float* op = attn + (size_t)(b * N_ + q) * C_ + head * 64;
#pragma unroll
        for (int db = 0; db < 2; ++db)
#pragma unroll
            for (int r = 0; r < 16; ++r) {
                int d = db * 32 + (r & 3) + 8 * (r >> 2) + 4 * h;
                op[d] = od[db][qb][r] * inv;
            }
    }
}

// ---------- host ----------
extern "C" void kernel_launch(void* const* d_in, const int* in_sizes, int n_in,
                              void* d_out, int out_size, void* d_ws, size_t ws_size,
                              hipStream_t stream) {
    const float* x      = (const float*)d_in[0];
    const float* qkv_w  = (const float*)d_in[1];
    const float* qkv_b  = (const float*)d_in[2];
    const float* proj_w = (const float*)d_in[3];
    const float* proj_b = (const float*)d_in[4];
    float* out = (float*)d_out;

    char* ws = (char*)d_ws;
    size_t off = 0;
    auto alloc = [&](size_t bytes) { size_t p = off; off += (bytes + 255) & ~(size_t)255; return p; };
    double* partial = (double*)(ws + alloc(256 * 2 * sizeof(double)));
    float*  scales  = (float*)(ws + alloc(4 * sizeof(float)));
    u16*    wq1     = (u16*)(ws + alloc((size_t)NW1 * 2));
    u16*    wq2     = (u16*)(ws + alloc((size_t)NW2 * 2));
    u16*    xq      = (u16*)(ws + alloc((size_t)BN_ * C_ * 2));   // reused as aq after GEMM1
    float*  rsx     = (float*)(ws + alloc((size_t)BN_ * 4));
    float*  rsa     = (float*)(ws + alloc((size_t)BN_ * 4));
    u16*    qg      = (u16*)(ws + alloc((size_t)B_ * H_ * N_ * D_ * 2));
    u16*    kg      = (u16*)(ws + alloc((size_t)B_ * H_ * N_ * D_ * 2));
    u16*    vtg     = (u16*)(ws + alloc((size_t)B_ * H_ * N_ * D_ * 2));
    float*  attn    = (float*)(ws + alloc((size_t)BN_ * C_ * 4));
    (void)ws_size; (void)in_sizes; (void)n_in; (void)out_size;

    k_wstats<<<256, 256, 0, stream>>>(qkv_w, proj_w, partial);
    k_wfinal<<<1, 256, 0, stream>>>(partial, scales);
    k_wquant<<<512, 256, 0, stream>>>(qkv_w, proj_w, scales, wq1, wq2);
    k_aquant<<<BN_, 128, 0, stream>>>(x, xq, rsx);
    k_gemm<0><<<dim3(BN_ / 128, O3_ / 128), 256, 0, stream>>>(xq, wq1, rsx, scales, qkv_b, qg, kg, vtg, nullptr);
    k_flash<<<B_ * H_ * (N_ / 128), 128, 0, stream>>>(qg, kg, vtg, attn);
    k_aquant<<<BN_, 128, 0, stream>>>(attn, xq, rsa);
    k_gemm<1><<<dim3(BN_ / 128, C_ / 128), 256, 0, stream>>>(xq, wq2, rsa, scales, proj_b, nullptr, nullptr, nullptr, out);
}

// Round 2
// 224.730 us; speedup vs baseline: 1.1599x; 1.1599x over previous
//
#include <hip/hip_runtime.h>
#include <hip/hip_bf16.h>

// ---------- types ----------
typedef short  s16x8  __attribute__((ext_vector_type(8)));   // 8 bf16 (4 VGPR)
typedef float  f32x4  __attribute__((ext_vector_type(4)));
typedef float  f32x16 __attribute__((ext_vector_type(16)));
typedef unsigned int u32x4 __attribute__((ext_vector_type(4)));
using u32 = unsigned int;
using u16 = unsigned short;
using as3u = __attribute__((address_space(3))) unsigned int;
using as1u = __attribute__((address_space(1))) unsigned int;

#define FINF __builtin_inff()

// problem constants
constexpr int B_  = 8;
constexpr int N_  = 2048;
constexpr int C_  = 384;
constexpr int H_  = 6;
constexpr int D_  = 64;
constexpr int BN_ = B_ * N_;        // 16384 tokens
constexpr int O3_ = 3 * C_;         // 1152
constexpr int NW1 = O3_ * C_;       // 442368 qkv weights
constexpr int NW2 = C_ * C_;        // 147456 proj weights
constexpr int BH_ = B_ * H_;        // 48

__device__ __forceinline__ u16 f2bf(float f) {
    union { float f; u32 u; } v; v.f = f;
    u32 r = v.u + 0x7FFFu + ((v.u >> 16) & 1u);   // RNE
    return (u16)(r >> 16);
}
__device__ __forceinline__ float exp2a(float x) {       // v_exp_f32 is 2^x
    float r; asm("v_exp_f32 %0, %1" : "=v"(r) : "v"(x)); return r;
}
__device__ __forceinline__ u32 cvtpk(float lo, float hi) {  // bf16(lo) | bf16(hi)<<16, RNE
    u32 r; asm("v_cvt_pk_bf16_f32 %0, %1, %2" : "=v"(r) : "v"(lo), "v"(hi)); return r;
}
__device__ __forceinline__ void plswap(u32& a, u32& b) {
    // a' = [a.lo31 | b.lo31], b' = [a.hi31 | b.hi31]
    asm("v_permlane32_swap_b32 %0, %1" : "+v"(a), "+v"(b));
}

// ---------- weight absmean (double partials for stability) ----------
__global__ void k_wstats(const float* __restrict__ w1, const float* __restrict__ w2,
                         double* __restrict__ partial) {
    double s1 = 0.0, s2 = 0.0;
    int t = blockIdx.x * 256 + threadIdx.x;
    const int stride = 256 * 256;
    for (int i = t; i < NW1; i += stride) s1 += (double)fabsf(w1[i]);
    for (int i = t; i < NW2; i += stride) s2 += (double)fabsf(w2[i]);
#pragma unroll
    for (int m = 1; m < 64; m <<= 1) { s1 += __shfl_xor(s1, m, 64); s2 += __shfl_xor(s2, m, 64); }
    __shared__ double r1[4], r2[4];
    int wid = threadIdx.x >> 6;
    if ((threadIdx.x & 63) == 0) { r1[wid] = s1; r2[wid] = s2; }
    __syncthreads();
    if (threadIdx.x == 0) {
        partial[2 * blockIdx.x]     = r1[0] + r1[1] + r1[2] + r1[3];
        partial[2 * blockIdx.x + 1] = r2[0] + r2[1] + r2[2] + r2[3];
    }
}

__global__ void k_wfinal(const double* __restrict__ partial, float* __restrict__ scales) {
    int t = threadIdx.x;  // 256 threads, 256 partial pairs
    double s1 = partial[2 * t], s2 = partial[2 * t + 1];
#pragma unroll
    for (int m = 1; m < 64; m <<= 1) { s1 += __shfl_xor(s1, m, 64); s2 += __shfl_xor(s2, m, 64); }
    __shared__ double r1[4], r2[4];
    if ((t & 63) == 0) { r1[t >> 6] = s1; r2[t >> 6] = s2; }
    __syncthreads();
    if (t == 0) {
        float m1 = (float)((r1[0] + r1[1] + r1[2] + r1[3]) / (double)NW1);
        float m2 = (float)((r2[0] + r2[1] + r2[2] + r2[3]) / (double)NW2);
        float sc1 = 1.f / fmaxf(m1, 1e-5f);
        float sc2 = 1.f / fmaxf(m2, 1e-5f);
        scales[0] = sc1; scales[1] = 1.f / sc1;
        scales[2] = sc2; scales[3] = 1.f / sc2;
    }
}

// ---------- ternary weight quant -> bf16 {-1,0,1} ----------
__global__ void k_wquant(const float* __restrict__ w1, const float* __restrict__ w2,
                         const float* __restrict__ scales,
                         u16* __restrict__ o1, u16* __restrict__ o2) {
    float sc1 = scales[0], sc2 = scales[2];
    int t = blockIdx.x * blockDim.x + threadIdx.x;
    int stride = gridDim.x * blockDim.x;
    for (int i = t; i < NW1; i += stride)
        o1[i] = f2bf(fminf(fmaxf(rintf(w1[i] * sc1), -1.f), 1.f));
    for (int i = t; i < NW2; i += stride)
        o2[i] = f2bf(fminf(fmaxf(rintf(w2[i] * sc2), -1.f), 1.f));
}

// ---------- per-token act quant: fp32 row(384) -> int-valued bf16 + 1/scale ----------
__global__ __launch_bounds__(128) void k_aquant(const float* __restrict__ in,
                                                u16* __restrict__ outq,
                                                float* __restrict__ rs) {
    int row = blockIdx.x;
    const float* xr = in + (size_t)row * C_;
    int t = threadIdx.x;
    float4 v = make_float4(0.f, 0.f, 0.f, 0.f);
    if (t < 96) v = ((const float4*)xr)[t];
    float mx = fmaxf(fmaxf(fabsf(v.x), fabsf(v.y)), fmaxf(fabsf(v.z), fabsf(v.w)));
#pragma unroll
    for (int m = 1; m < 64; m <<= 1) mx = fmaxf(mx, __shfl_xor(mx, m, 64));
    __shared__ float red[2];
    if ((t & 63) == 0) red[t >> 6] = mx;
    __syncthreads();
    mx = fmaxf(red[0], red[1]);
    float scale = 128.f / fmaxf(mx, 1e-5f);
    if (t == 0) rs[row] = 1.f / scale;
    if (t < 96) {
        ushort4 o;
        o.x = f2bf(fminf(fmaxf(rintf(v.x * scale), -128.f), 127.f));
        o.y = f2bf(fminf(fmaxf(rintf(v.y * scale), -128.f), 127.f));
        o.z = f2bf(fminf(fmaxf(rintf(v.z * scale), -128.f), 127.f));
        o.w = f2bf(fminf(fmaxf(rintf(v.w * scale), -128.f), 127.f));
        ((ushort4*)(outq + (size_t)row * C_))[t] = o;
    }
}

// ---------- GEMM: C[m,o] = sum_c A[m,c]*W[o,c]; dequant epilogue ----------
// MODE 0: N=1152, scatter to q(scaled log2e/8)/k [bh][n][d] and v^T [bh][d][n] (bf16)
// MODE 1: N=384, write fp32 out
template <int MODE>
__global__ __launch_bounds__(256) void k_gemm(const u16* __restrict__ A, const u16* __restrict__ W,
                                              const float* __restrict__ rs, const float* __restrict__ scales,
                                              const float* __restrict__ bias,
                                              u16* __restrict__ qg, u16* __restrict__ kg, u16* __restrict__ vtg,
                                              float* __restrict__ fout) {
    constexpr int K = C_;
    __shared__ u16 As[128 * 64];
    __shared__ u16 Bs[128 * 64];
    int m0 = blockIdx.x * 128, n0 = blockIdx.y * 128;
    int tid = threadIdx.x, lane = tid & 63, wid = tid >> 6;
    int wm = wid >> 1, wn = wid & 1;

    f32x4 acc[4][4];
#pragma unroll
    for (int a = 0; a < 4; ++a)
#pragma unroll
        for (int b = 0; b < 4; ++b)
#pragma unroll
            for (int r = 0; r < 4; ++r) acc[a][b][r] = 0.f;

    for (int k0 = 0; k0 < K; k0 += 64) {
#pragma unroll
        for (int t = 0; t < 4; ++t) {
            int chunk = t * 256 + wid * 64 + lane;       // 16B chunks, per-lane
            int row = chunk >> 3, c8 = chunk & 7;
            const u16* srcA = A + (size_t)(m0 + row) * K + k0 + c8 * 8;
            const u16* srcB = W + (size_t)(n0 + row) * K + k0 + c8 * 8;
            __builtin_amdgcn_global_load_lds((const as1u*)srcA, (as3u*)(As + (size_t)(t * 256 + wid * 64) * 8), 16, 0, 0);
            __builtin_amdgcn_global_load_lds((const as1u*)srcB, (as3u*)(Bs + (size_t)(t * 256 + wid * 64) * 8), 16, 0, 0);
        }
        __syncthreads();
#pragma unroll
        for (int kk = 0; kk < 2; ++kk) {
            s16x8 ar[4], br[4];
#pragma unroll
            for (int f = 0; f < 4; ++f) {
                ar[f] = *(const s16x8*)(As + (wm * 64 + f * 16 + (lane & 15)) * 64 + kk * 32 + (lane >> 4) * 8);
                br[f] = *(const s16x8*)(Bs + (wn * 64 + f * 16 + (lane & 15)) * 64 + kk * 32 + (lane >> 4) * 8);
            }
#pragma unroll
            for (int fr = 0; fr < 4; ++fr)
#pragma unroll
                for (int fc = 0; fc < 4; ++fc)
                    acc[fr][fc] = __builtin_amdgcn_mfma_f32_16x16x32_bf16(ar[fr], br[fc], acc[fr][fc], 0, 0, 0);
        }
        __syncthreads();
    }

    float rsw = scales[MODE == 0 ? 1 : 3];
    int colg = lane & 15, rowb = (lane >> 4) * 4;
#pragma unroll
    for (int fr = 0; fr < 4; ++fr) {
#pragma unroll
        for (int r = 0; r < 4; ++r) {
            int m = m0 + wm * 64 + fr * 16 + rowb + r;
            float rsm = rs[m] * rsw;
#pragma unroll
            for (int fc = 0; fc < 4; ++fc) {
                int o = n0 + wn * 64 + fc * 16 + colg;
                float val = acc[fr][fc][r] * rsm + bias[o];
                if (MODE == 0) {
                    int b = m >> 11, n = m & 2047;
                    if (o < C_) {
                        int hh = o >> 6, d = o & 63;
                        // fold softmax scale D^-0.5 = 1/8 AND log2(e) into q
                        qg[(size_t)(b * H_ + hh) * (N_ * D_) + n * 64 + d] = f2bf(val * (0.125f * 1.44269504088896f));
                    } else if (o < 2 * C_) {
                        int oo = o - C_; int hh = oo >> 6, d = oo & 63;
                        kg[(size_t)(b * H_ + hh) * (N_ * D_) + n * 64 + d] = f2bf(val);
                    } else {
                        int oo = o - 2 * C_; int hh = oo >> 6, d = oo & 63;
                        vtg[(size_t)(b * H_ + hh) * (N_ * D_) + (size_t)d * N_ + n] = f2bf(val);
                    }
                } else {
                    fout[(size_t)m * C_ + o] = val;
                }
            }
        }
    }
}

// ---------- flash attention, split-KV ----------
// S^T = K.Q^T (swapped) in log2 domain, softmax in-lane (defer-max THR=8),
// P pack via v_cvt_pk_bf16_f32 + v_permlane32_swap, O^T = V^T.P^T.
// grid: 2 splits x 48 bh x 16 qtiles, block = 128 (2 waves, 64 q-rows/wave, 1024 kv/wave)
__global__ __launch_bounds__(128, 3) void k_flash(const u16* __restrict__ qg, const u16* __restrict__ kg,
                                                  const u16* __restrict__ vtg,
                                                  float* __restrict__ pod, float* __restrict__ pml) {
    int i = blockIdx.x;
    int bh = (i & 7) * 6 + ((i >> 3) % 6);   // same-bh blocks share XCD (i%8 fixed)
    int x  = (i >> 3) / 6;                   // 0..31
    int qt = x & 15;
    int split = x >> 4;
    int lane = threadIdx.x & 63;
    int wid = threadIdx.x >> 6;              // 0..1
    int h = lane >> 5;                       // lane half
    int ql = lane & 31;
    const u16* Qb = qg + (size_t)bh * (N_ * D_);
    const u16* Kb = kg + (size_t)bh * (N_ * D_);
    const u16* Vb = vtg + (size_t)bh * (N_ * D_);
    int q0 = qt * 128 + wid * 64;
    int kv_beg = split * (N_ / 2);

    // Q^T B-frags, resident: qf[qb][cs], element j: Q[q0+qb*32+ql][cs*16+h*8+j]
    s16x8 qf[2][4];
#pragma unroll
    for (int qb = 0; qb < 2; ++qb)
#pragma unroll
        for (int cs = 0; cs < 4; ++cs)
            qf[qb][cs] = *(const s16x8*)(Qb + (size_t)(q0 + qb * 32 + ql) * 64 + cs * 16 + h * 8);

    f32x16 od[2][2];   // [db][qb], O^T acc: col=q(lane&31), row=d
#pragma unroll
    for (int a = 0; a < 2; ++a)
#pragma unroll
        for (int b = 0; b < 2; ++b)
#pragma unroll
            for (int r = 0; r < 16; ++r) od[a][b][r] = 0.f;

    float mrun[2] = { -FINF, -FINF };
    float lrun[2] = { 0.f, 0.f };

    for (int t = 0; t < (N_ / 2) / 32; ++t) {
        int kv0 = kv_beg + t * 32;
        s16x8 kf[4], vf[2][2];
#pragma unroll
        for (int cs = 0; cs < 4; ++cs)
            kf[cs] = *(const s16x8*)(Kb + (size_t)(kv0 + ql) * 64 + cs * 16 + h * 8);
#pragma unroll
        for (int db = 0; db < 2; ++db)
#pragma unroll
            for (int ks = 0; ks < 2; ++ks)
                vf[db][ks] = *(const s16x8*)(Vb + (size_t)(db * 32 + ql) * N_ + kv0 + ks * 16 + h * 8);

#pragma unroll
        for (int qb = 0; qb < 2; ++qb) {
            f32x16 s;
#pragma unroll
            for (int r = 0; r < 16; ++r) s[r] = 0.f;
#pragma unroll
            for (int cs = 0; cs < 4; ++cs)
                s = __builtin_amdgcn_mfma_f32_32x32x16_bf16(kf[cs], qf[qb][cs], s, 0, 0, 0);

            // row max over this lane's 16 k-rows (pairwise tree), then pair-combine
            float m0a = fmaxf(s[0], s[1]),   m1a = fmaxf(s[2], s[3]);
            float m2a = fmaxf(s[4], s[5]),   m3a = fmaxf(s[6], s[7]);
            float m4a = fmaxf(s[8], s[9]),   m5a = fmaxf(s[10], s[11]);
            float m6a = fmaxf(s[12], s[13]), m7a = fmaxf(s[14], s[15]);
            float mx = fmaxf(fmaxf(fmaxf(m0a, m1a), fmaxf(m2a, m3a)),
                             fmaxf(fmaxf(m4a, m5a), fmaxf(m6a, m7a)));
            mx = fmaxf(mx, __shfl_xor(mx, 32, 64));
            // defer-max: only rescale when tile max exceeds running max by > 8 (log2 units)
            if (!__all(mx <= mrun[qb] + 8.f)) {
                float mnew = fmaxf(mrun[qb], mx);
                float fsc = exp2a(mrun[qb] - mnew);
                lrun[qb] *= fsc;
#pragma unroll
                for (int r = 0; r < 16; ++r) { od[0][qb][r] *= fsc; od[1][qb][r] *= fsc; }
                mrun[qb] = mnew;
            }
            float m = mrun[qb];
            float ps0 = 0.f, ps1 = 0.f, ps2 = 0.f, ps3 = 0.f;
#pragma unroll
            for (int r = 0; r < 16; r += 4) {
                float p0 = exp2a(s[r] - m);     float p1 = exp2a(s[r + 1] - m);
                float p2 = exp2a(s[r + 2] - m); float p3 = exp2a(s[r + 3] - m);
                s[r] = p0; s[r + 1] = p1; s[r + 2] = p2; s[r + 3] = p3;
                ps0 += p0; ps1 += p1; ps2 += p2; ps3 += p3;
            }
            lrun[qb] += (ps0 + ps1) + (ps2 + ps3);

            // pack P^T into B-frags: pf[ks] rows ks*16+h*8+j, col ql
#pragma unroll
            for (int ks = 0; ks < 2; ++ks) {
                const int bse = ks * 8;
                u32 A0 = cvtpk(s[bse + 0], s[bse + 1]);
                u32 A1 = cvtpk(s[bse + 2], s[bse + 3]);
                u32 B0 = cvtpk(s[bse + 4], s[bse + 5]);
                u32 B1 = cvtpk(s[bse + 6], s[bse + 7]);
                plswap(A0, B0);
                plswap(A1, B1);
                u32x4 pw; pw[0] = A0; pw[1] = A1; pw[2] = B0; pw[3] = B1;
                s16x8 pf = __builtin_bit_cast(s16x8, pw);
                od[0][qb] = __builtin_amdgcn_mfma_f32_32x32x16_bf16(vf[0][ks], pf, od[0][qb], 0, 0, 0);
                od[1][qb] = __builtin_amdgcn_mfma_f32_32x32x16_bf16(vf[1][ks], pf, od[1][qb], 0, 0, 0);
            }
        }
    }

    // store unnormalized partials + (m, l)
#pragma unroll
    for (int qb = 0; qb < 2; ++qb) {
        float ltot = lrun[qb] + __shfl_xor(lrun[qb], 32, 64);
        int q = q0 + qb * 32 + ql;
        float* op = pod + ((size_t)(split * BH_ + bh) * N_ + q) * 64;
#pragma unroll
        for (int db = 0; db < 2; ++db)
#pragma unroll
            for (int r = 0; r < 16; ++r) {
                int d = db * 32 + (r & 3) + 8 * (r >> 2) + 4 * h;
                op[d] = od[db][qb][r];
            }
        if (h == 0) {
            float* mlp = pml + ((size_t)(split * BH_ + bh) * N_ + q) * 2;
            mlp[0] = mrun[qb]; mlp[1] = ltot;
        }
    }
}

// ---------- combine the 2 KV-splits ----------
__global__ __launch_bounds__(256) void k_combine(const float* __restrict__ pod,
                                                 const float* __restrict__ pml,
                                                 float* __restrict__ attn) {
    int e = blockIdx.x * 256 + threadIdx.x;   // < 48*2048*16
    int d4 = e & 15;
    int q  = (e >> 4) & (N_ - 1);
    int bh = e >> 15;
    const float2* ml = (const float2*)pml;
    float2 ml0 = ml[(size_t)bh * N_ + q];
    float2 ml1 = ml[(size_t)(BH_ + bh) * N_ + q];
    float m = fmaxf(ml0.x, ml1.x);
    float w0 = exp2a(ml0.x - m), w1 = exp2a(ml1.x - m);
    float inv = 1.f / (w0 * ml0.y + w1 * ml1.y);
    float4 a = ((const float4*)(pod + ((size_t)bh * N_ + q) * 64))[d4];
    float4 b = ((const float4*)(pod + ((size_t)(BH_ + bh) * N_ + q) * 64))[d4];
    float4 o;
    o.x = (a.x * w0 + b.x * w1) * inv;
    o.y = (a.y * w0 + b.y * w1) * inv;
    o.z = (a.z * w0 + b.z * w1) * inv;
    o.w = (a.w * w0 + b.w * w1) * inv;
    int bb = bh / H_, head = bh - bb * H_;
    ((float4*)(attn + ((size_t)(bb * N_ + q)) * C_ + head * 64))[d4] = o;
}

// ---------- host ----------
extern "C" void kernel_launch(void* const* d_in, const int* in_sizes, int n_in,
                              void* d_out, int out_size, void* d_ws, size_t ws_size,
                              hipStream_t stream) {
    const float* x      = (const float*)d_in[0];
    const float* qkv_w  = (const float*)d_in[1];
    const float* qkv_b  = (const float*)d_in[2];
    const float* proj_w = (const float*)d_in[3];
    const float* proj_b = (const float*)d_in[4];
    float* out = (float*)d_out;

    char* ws = (char*)d_ws;
    size_t off = 0;
    auto alloc = [&](size_t bytes) { size_t p = off; off += (bytes + 255) & ~(size_t)255; return p; };
    double* partial = (double*)(ws + alloc(256 * 2 * sizeof(double)));
    float*  scales  = (float*)(ws + alloc(4 * sizeof(float)));
    u16*    wq1     = (u16*)(ws + alloc((size_t)NW1 * 2));
    u16*    wq2     = (u16*)(ws + alloc((size_t)NW2 * 2));
    u16*    xq      = (u16*)(ws + alloc((size_t)BN_ * C_ * 2));   // reused as aq after GEMM1
    float*  rsx     = (float*)(ws + alloc((size_t)BN_ * 4));
    float*  rsa     = (float*)(ws + alloc((size_t)BN_ * 4));
    u16*    qg      = (u16*)(ws + alloc((size_t)BH_ * N_ * D_ * 2));
    u16*    kg      = (u16*)(ws + alloc((size_t)BH_ * N_ * D_ * 2));
    u16*    vtg     = (u16*)(ws + alloc((size_t)BH_ * N_ * D_ * 2));
    float*  attn    = (float*)(ws + alloc((size_t)BN_ * C_ * 4));
    float*  pod     = (float*)(ws + alloc((size_t)2 * BH_ * N_ * 64 * 4));
    float*  pml     = (float*)(ws + alloc((size_t)2 * BH_ * N_ * 2 * 4));
    (void)ws_size; (void)in_sizes; (void)n_in; (void)out_size;

    k_wstats<<<256, 256, 0, stream>>>(qkv_w, proj_w, partial);
    k_wfinal<<<1, 256, 0, stream>>>(partial, scales);
    k_wquant<<<512, 256, 0, stream>>>(qkv_w, proj_w, scales, wq1, wq2);
    k_aquant<<<BN_, 128, 0, stream>>>(x, xq, rsx);
    k_gemm<0><<<dim3(BN_ / 128, O3_ / 128), 256, 0, stream>>>(xq, wq1, rsx, scales, qkv_b, qg, kg, vtg, nullptr);
    k_flash<<<2 * BH_ * (N_ / 128), 128, 0, stream>>>(qg, kg, vtg, pod, pml);
    k_combine<<<(BH_ * N_ * 16) / 256, 256, 0, stream>>>(pod, pml, attn);
    k_aquant<<<BN_, 128, 0, stream>>>(attn, xq, rsa);
    k_gemm<1><<<dim3(BN_ / 128, C_ / 128), 256, 0, stream>>>(xq, wq2, rsa, scales, proj_b, nullptr, nullptr, nullptr, out);
}